// Round 1
// baseline (127.098 us; speedup 1.0000x reference)
//
#include <hip/hip_runtime.h>

// Problem constants: T=1024, B=256, H=20
#define T_N 1024
#define B_N 256
#define H_N 20
#define NW  8            // waves per block
#define NDW (NW - 1)     // dot waves
#define SIH 1096         // I-history row stride in HALVES (conflict-free layout, see R5)

typedef _Float16 h8_t __attribute__((ext_vector_type(8)));

#if __has_builtin(__builtin_amdgcn_fdot2)
#define DOT8(acc, mv, iv)                                                           \
    acc = __builtin_amdgcn_fdot2(__builtin_shufflevector(mv, mv, 0, 1),             \
                                 __builtin_shufflevector(iv, iv, 0, 1), acc, false);\
    acc = __builtin_amdgcn_fdot2(__builtin_shufflevector(mv, mv, 2, 3),             \
                                 __builtin_shufflevector(iv, iv, 2, 3), acc, false);\
    acc = __builtin_amdgcn_fdot2(__builtin_shufflevector(mv, mv, 4, 5),             \
                                 __builtin_shufflevector(iv, iv, 4, 5), acc, false);\
    acc = __builtin_amdgcn_fdot2(__builtin_shufflevector(mv, mv, 6, 7),             \
                                 __builtin_shufflevector(iv, iv, 6, 7), acc, false);
#else
#define DOT8(acc, mv, iv)                                                           \
    _Pragma("unroll")                                                               \
    for (int _k = 0; _k < 8; ++_k) acc = fmaf((float)mv[_k], (float)iv[_k], acc);
#endif

__device__ __forceinline__ float rdlane_i(float v, int lane) {
    return __uint_as_float((unsigned)__builtin_amdgcn_readlane((int)__float_as_uint(v), lane));
}
__device__ __forceinline__ float fast_tanh(float x) {
    const float e = __expf(2.0f * x);
    return fmaf(-2.0f, __builtin_amdgcn_rcpf(e + 1.0f), 1.0f);
}
__device__ __forceinline__ float fast_sigmoid(float x) {
    return __builtin_amdgcn_rcpf(1.0f + __expf(-x));
}

// explicit literal-token repetition (tokens must be plain literals for ##)
#define REP64(F) \
    F(0) F(1) F(2) F(3) F(4) F(5) F(6) F(7) F(8) F(9) F(10) F(11) F(12) F(13) \
    F(14) F(15) F(16) F(17) F(18) F(19) F(20) F(21) F(22) F(23) F(24) F(25)   \
    F(26) F(27) F(28) F(29) F(30) F(31) F(32) F(33) F(34) F(35) F(36) F(37)   \
    F(38) F(39) F(40) F(41) F(42) F(43) F(44) F(45) F(46) F(47) F(48) F(49)   \
    F(50) F(51) F(52) F(53) F(54) F(55) F(56) F(57) F(58) F(59) F(60) F(61)   \
    F(62) F(63)

// ---------------------------------------------------------------------------
// Single fused kernel. 256 blocks (1/batch) x 512 threads (8 waves).
// Phase A: all waves compute me[1024] -> fp32 sMeF + fp16 sMeH.
// Phase B: wave 0 = serial SIR chain with me-tables held in 128 NAMED scalar
//          variables; waves 1-7 = fp16 fdot2 history dots (R5 layout).
//          NO global stores inside the chunk loop: per-chunk results go to
//          sS/sI in LDS (2 ds_write_b32), so the compiler's mandatory
//          s_waitcnt vmcnt(0)-before-s_barrier no longer drains a 128-line
//          scattered store every chunk.
// Phase C: all 8 waves compute R + difference-quotient diffs from LDS and
//          issue the scattered output stores in one overlapped burst.
// ---------------------------------------------------------------------------
__global__ __launch_bounds__(512, 1) void scan_kernel(
    const float* __restrict__ t,
    const float* __restrict__ y,
    const float* __restrict__ w1, const float* __restrict__ b1,
    const float* __restrict__ w2, const float* __restrict__ b2,
    const float* __restrict__ w3, const float* __restrict__ b3,
    const float* __restrict__ w4, const float* __restrict__ b4,
    const float* __restrict__ beta_p,
    const float* __restrict__ gamma_p,
    float* __restrict__ out)     // [solution (T*B*3) | diff (T*B*3)]
{
    __shared__ __align__(16) float    sMeF[T_N];      // fp32 me (serial tables + fixup)
    __shared__ __align__(16) _Float16 sMeH[T_N];      // fp16 me (dot operand A)
    __shared__ __align__(16) _Float16 sIhR[8 * SIH];  // 8 shifted fp16 I-history rows
    __shared__ __align__(16) float    sS[T_N];        // fp32 S trajectory (deferred output)
    __shared__ __align__(16) float    sI[T_N];        // fp32 I trajectory (deferred output)
    __shared__ float P[2][NDW][64];

    const int b   = blockIdx.x;
    const int tid = threadIdx.x;
    const int wid = tid >> 6;
    const int L   = tid & 63;

    // per-lane dot-geometry constants (chunk-invariant)
    const int f    = (-L) & 7;            // misalignment of lane L's me window
    const int R8   = L + f;               // L rounded up to multiple of 8
    const int row  = L & 7;               // I-history row for this lane
    const int iofs = row * SIH + (f ? 0 : 8);

    // zero the row front-pads (slots representing I[<0])
    if (tid < 64) sIhR[(tid >> 3) * SIH + (tid & 7)] = (_Float16)0.0f;

    // ---- Phase A: me MLP (2 values/thread) ----
#pragma unroll
    for (int v = 0; v < 2; ++v) {
        const int mi = tid + v * 512;
        const float x = t[mi];

        float h1[H_N], h2[H_N];
#pragma unroll
        for (int k = 0; k < H_N; ++k) h1[k] = fast_tanh(fmaf(x, w1[k], b1[k]));

#pragma unroll 4
        for (int k = 0; k < H_N; ++k) {
            float a = b2[k];
#pragma unroll
            for (int j = 0; j < H_N; ++j) a = fmaf(h1[j], w2[j * H_N + k], a);
            h2[k] = fast_tanh(a);
        }

        float a4 = b4[0];
#pragma unroll 4
        for (int k = 0; k < H_N; ++k) {
            float a = b3[k];
#pragma unroll
            for (int j = 0; j < H_N; ++j) a = fmaf(h2[j], w3[j * H_N + k], a);
            a4 = fmaf(fast_tanh(a), w4[k], a4);
        }

        const float meval = fast_sigmoid(a4);
        sMeF[mi] = meval;
        sMeH[mi] = (_Float16)meval;
    }

    // ---- scalars / state ----
    const float dt    = t[0] - t[1];
    const float beta  = beta_p[0];
    const float gma   = gamma_p[0];
    const float invdt = 1.0f / dt;

    const float S0 = y[b * 3 + 0];
    const float I0 = y[b * 3 + 1];
    const float R0 = y[b * 3 + 2];
    const float TOT = S0 + I0 + R0;     // SIR total conserved

    // publish I[0] into all 8 rows
    if (tid < 8) sIhR[tid * SIH + 8 - tid] = (_Float16)I0;

    float* __restrict__ diff = out + (size_t)T_N * B_N * 3;

    __syncthreads();   // sMeF/sMeH/pads/I0 visible

    // fixup me weights (chunk-invariant): mf[d-1] = me[960 - L - d]
    float mf[7];
#pragma unroll
    for (int d = 1; d <= 7; ++d) mf[d - 1] = sMeF[T_N - 64 - L - d];

    const float dtb  = dt * beta;
    const float ndtg = -dt * gma;
    const float dt2  = dt * dt;
    const float meT1 = sMeF[T_N - 1];

    float S = S0, I = I0, oS = S0, oI = I0;
    float acc_cur = 0.0f, acc_nxt = 0.0f, pre = 0.0f;

    // register me-tables: 128 NAMED scalars (no array, no alloca, no SROA)
#define TBLDECL(k) float rm_##k, rn_##k;
    REP64(TBLDECL)
#undef TBLDECL
    if (wid == 0) {
#define TBLINIT(k)                                                      \
        rm_##k = ((k) < L) ? sMeF[T_N - L + (k)] : 0.0f;                \
        rn_##k = sMeF[T_N - 64 - L + (k)];
        REP64(TBLINIT)
#undef TBLINIT
    }

    // serial step M_: entering (S,I) = y_{64c+M_-1}; produces y_{64c+M_}.
    // pre was read BEFORE step (M_-1)'s fold -> patch with meT1*I.
    // Longest dependency cycle: I->bI->q->{I',s1->S'} = 3 VALU ops.
#define STEPB(M_, FIRST_)                                               \
    {                                                                   \
        const float sum = (FIRST_) ? pre : fmaf(meT1, I, pre);          \
        float pnx = pre;                                                \
        if ((M_) < 63) pnx = rdlane_i(acc_cur, (M_) + 1);               \
        const float bI = dtb * I;                                       \
        const float i1 = fmaf(ndtg, I, I);                              \
        const float q  = bI * S;                                        \
        const float s1 = S - q;                                         \
        S = fmaf(dt2, sum, s1);                                         \
        I = i1 + q;                                                     \
        const bool cap = (L == (M_));                                   \
        oS = cap ? S : oS;                                              \
        oI = cap ? I : oI;                                              \
        acc_cur = fmaf(rm_##M_, I, acc_cur);                            \
        acc_nxt = fmaf(rn_##M_, I, acc_nxt);                            \
        pre = pnx;                                                      \
    }
#define STEP_GE1(M_) if ((M_) >= 1) STEPB(M_, false)
#define STEP_GE2(M_) if ((M_) >= 2) STEPB(M_, false)

    for (int c = 0; c < 16; ++c) {
        if (wid == 0) {
            if (c == 0) {
                // fold initial I0 (t=0 term); lane0's rm_0 is the 0 pad
                acc_cur = rm_0 * I;
                acc_nxt = rn_0 * I;
                pre = rdlane_i(acc_cur, 1);
                STEPB(1, true)
                REP64(STEP_GE2)
            } else {
                float ac = acc_nxt;
#pragma unroll
                for (int w = 0; w < NDW; ++w) ac += P[c & 1][w][L];
                acc_cur = ac;
                acc_nxt = 0.0f;
                pre = rdlane_i(acc_cur, 0);
                STEPB(0, true)
                REP64(STEP_GE1)
            }

            // ---- chunk epilogue (wave 0): LDS only, no global traffic ----
            const int j = 64 * c + L;
            const _Float16 hI = (_Float16)oI;
#pragma unroll
            for (int r = 0; r < 8; ++r) sIhR[r * SIH + 8 + (j - r)] = hI;
            sS[j] = oS;
            sI[j] = oI;
        } else if (c < 15) {
            // history dot for chunk c+1 over tau < 64c (R5 layout, unchanged)
            const int w    = wid - 1;
            const int G    = 8 * c;
            const int idx0 = (T_N - 64 * (c + 1)) - R8;
            float p0 = 0.0f, p1 = 0.0f;
            int s = w;
            for (; s + NDW < G; s += 2 * NDW) {
                const h8_t mv0 = *(const h8_t*)&sMeH[idx0 + 8 * s];
                const h8_t iv0 = *(const h8_t*)&sIhR[iofs + 8 * s];
                const h8_t mv1 = *(const h8_t*)&sMeH[idx0 + 8 * (s + NDW)];
                const h8_t iv1 = *(const h8_t*)&sIhR[iofs + 8 * (s + NDW)];
                DOT8(p0, mv0, iv0)
                DOT8(p1, mv1, iv1)
            }
            if (s < G) {
                const h8_t mv0 = *(const h8_t*)&sMeH[idx0 + 8 * s];
                const h8_t iv0 = *(const h8_t*)&sIhR[iofs + 8 * s];
                DOT8(p0, mv0, iv0)
            }
            float p = p0 + p1;
            if (w == 0) {
                // tail fixup: tau = 64c - d, d = 1..f
#pragma unroll
                for (int d = 1; d <= 7; ++d) {
                    const float ih = (float)sIhR[8 + 64 * c - d];   // row 0
                    if (d <= f) p = fmaf(mf[d - 1], ih, p);
                }
            }
            P[(c + 1) & 1][w][L] = p;
        }
        __syncthreads();
    }
#undef STEPB
#undef STEP_GE1
#undef STEP_GE2

    // ---- Phase C: deferred output. All 8 waves, one overlapped store burst.
    // (last loop iteration's __syncthreads made sS/sI fully visible)
#pragma unroll
    for (int v = 0; v < 2; ++v) {
        const int j = tid + v * 512;
        const float Sj = sS[j];
        const float Ij = sI[j];
        const float Rj = TOT - Sj - Ij;
        const size_t so = ((size_t)j * B_N + b) * 3;
        out[so + 0] = Sj;
        out[so + 1] = Ij;
        out[so + 2] = Rj;

        float d0 = 0.0f, d1 = 0.0f, d2 = 0.0f;
        if (j < T_N - 1) {
            d0 = (sS[j + 1] - Sj) * invdt;
            d1 = (sI[j + 1] - Ij) * invdt;
            d2 = -d0 - d1;
        }
        diff[so + 0] = d0;
        diff[so + 1] = d1;
        diff[so + 2] = d2;
    }
}

// ---------------------------------------------------------------------------
// Launcher
// ---------------------------------------------------------------------------
extern "C" void kernel_launch(void* const* d_in, const int* in_sizes, int n_in,
                              void* d_out, int out_size, void* d_ws, size_t ws_size,
                              hipStream_t stream) {
    const float* t     = (const float*)d_in[0];
    const float* y     = (const float*)d_in[1];
    const float* w1    = (const float*)d_in[2];
    const float* b1    = (const float*)d_in[3];
    const float* w2    = (const float*)d_in[4];
    const float* b2    = (const float*)d_in[5];
    const float* w3    = (const float*)d_in[6];
    const float* b3    = (const float*)d_in[7];
    const float* w4    = (const float*)d_in[8];
    const float* b4    = (const float*)d_in[9];
    const float* beta  = (const float*)d_in[10];
    const float* gamma = (const float*)d_in[11];

    scan_kernel<<<B_N, 512, 0, stream>>>(t, y, w1, b1, w2, b2, w3, b3, w4, b4,
                                         beta, gamma, (float*)d_out);
}

// Round 2
// 121.766 us; speedup vs baseline: 1.0438x; 1.0438x over previous
//
#include <hip/hip_runtime.h>

// Problem constants: T=1024, B=256, H=20
#define T_N 1024
#define B_N 256
#define H_N 20
#define NW  8            // waves per block
#define NDW (NW - 1)     // dot waves
#define SIH 1096         // I-history row stride in HALVES (conflict-free layout, see R5)

typedef _Float16 h8_t __attribute__((ext_vector_type(8)));

#if __has_builtin(__builtin_amdgcn_fdot2)
#define DOT8(acc, mv, iv)                                                           \
    acc = __builtin_amdgcn_fdot2(__builtin_shufflevector(mv, mv, 0, 1),             \
                                 __builtin_shufflevector(iv, iv, 0, 1), acc, false);\
    acc = __builtin_amdgcn_fdot2(__builtin_shufflevector(mv, mv, 2, 3),             \
                                 __builtin_shufflevector(iv, iv, 2, 3), acc, false);\
    acc = __builtin_amdgcn_fdot2(__builtin_shufflevector(mv, mv, 4, 5),             \
                                 __builtin_shufflevector(iv, iv, 4, 5), acc, false);\
    acc = __builtin_amdgcn_fdot2(__builtin_shufflevector(mv, mv, 6, 7),             \
                                 __builtin_shufflevector(iv, iv, 6, 7), acc, false);
#else
#define DOT8(acc, mv, iv)                                                           \
    _Pragma("unroll")                                                               \
    for (int _k = 0; _k < 8; ++_k) acc = fmaf((float)mv[_k], (float)iv[_k], acc);
#endif

__device__ __forceinline__ float rdlane_i(float v, int lane) {
    return __uint_as_float((unsigned)__builtin_amdgcn_readlane((int)__float_as_uint(v), lane));
}
__device__ __forceinline__ float fast_tanh(float x) {
    const float e = __expf(2.0f * x);
    return fmaf(-2.0f, __builtin_amdgcn_rcpf(e + 1.0f), 1.0f);
}
__device__ __forceinline__ float fast_sigmoid(float x) {
    return __builtin_amdgcn_rcpf(1.0f + __expf(-x));
}

// explicit literal-token repetition (tokens must be plain literals for ##)
#define REP64(F) \
    F(0) F(1) F(2) F(3) F(4) F(5) F(6) F(7) F(8) F(9) F(10) F(11) F(12) F(13) \
    F(14) F(15) F(16) F(17) F(18) F(19) F(20) F(21) F(22) F(23) F(24) F(25)   \
    F(26) F(27) F(28) F(29) F(30) F(31) F(32) F(33) F(34) F(35) F(36) F(37)   \
    F(38) F(39) F(40) F(41) F(42) F(43) F(44) F(45) F(46) F(47) F(48) F(49)   \
    F(50) F(51) F(52) F(53) F(54) F(55) F(56) F(57) F(58) F(59) F(60) F(61)   \
    F(62) F(63)

// ---------------------------------------------------------------------------
// Single fused kernel. 256 blocks (1/batch) x 512 threads (8 waves).
// Phase A: all waves compute me[1024] -> fp32 sMeF + fp16 sMeH.
// Phase B: wave 0 = serial SIR chain with me-tables held in 128 NAMED scalar
//          variables; waves 1-7 = fp16 fdot2 history dots (R5 layout).
//
// R2 change: pin the 128 table scalars into VGPRs with opaque asm after init.
// Evidence (R0/R1 rocprof): VGPR_Count=88-92 < 128 live table values, no
// scratch traffic -> compiler was REMATERIALIZING rm_k/rn_k as per-step
// ds_read_b32 from sMeF inside the serial chain (~2 x 120cy exposed LDS
// latency per step = the observed ~110 cy/step). asm volatile("":"+v"(x))
// makes the def opaque -> no legal remat -> values stay register-resident.
//
// Per-chunk global stores from wave 0 are kept (R1 showed they are fully
// overlapped: __syncthreads drains lgkmcnt only, not global stores).
// ---------------------------------------------------------------------------
__global__ __launch_bounds__(512, 1) void scan_kernel(
    const float* __restrict__ t,
    const float* __restrict__ y,
    const float* __restrict__ w1, const float* __restrict__ b1,
    const float* __restrict__ w2, const float* __restrict__ b2,
    const float* __restrict__ w3, const float* __restrict__ b3,
    const float* __restrict__ w4, const float* __restrict__ b4,
    const float* __restrict__ beta_p,
    const float* __restrict__ gamma_p,
    float* __restrict__ out)     // [solution (T*B*3) | diff (T*B*3)]
{
    __shared__ __align__(16) float    sMeF[T_N];      // fp32 me (serial tables + fixup)
    __shared__ __align__(16) _Float16 sMeH[T_N];      // fp16 me (dot operand A)
    __shared__ __align__(16) _Float16 sIhR[8 * SIH];  // 8 shifted fp16 I-history rows
    __shared__ float P[2][NDW][64];

    const int b   = blockIdx.x;
    const int tid = threadIdx.x;
    const int wid = tid >> 6;
    const int L   = tid & 63;

    // per-lane dot-geometry constants (chunk-invariant)
    const int f    = (-L) & 7;            // misalignment of lane L's me window
    const int R8   = L + f;               // L rounded up to multiple of 8
    const int row  = L & 7;               // I-history row for this lane
    const int iofs = row * SIH + (f ? 0 : 8);

    // zero the row front-pads (slots representing I[<0])
    if (tid < 64) sIhR[(tid >> 3) * SIH + (tid & 7)] = (_Float16)0.0f;

    // ---- Phase A: me MLP (2 values/thread) ----
#pragma unroll
    for (int v = 0; v < 2; ++v) {
        const int mi = tid + v * 512;
        const float x = t[mi];

        float h1[H_N], h2[H_N];
#pragma unroll
        for (int k = 0; k < H_N; ++k) h1[k] = fast_tanh(fmaf(x, w1[k], b1[k]));

#pragma unroll 4
        for (int k = 0; k < H_N; ++k) {
            float a = b2[k];
#pragma unroll
            for (int j = 0; j < H_N; ++j) a = fmaf(h1[j], w2[j * H_N + k], a);
            h2[k] = fast_tanh(a);
        }

        float a4 = b4[0];
#pragma unroll 4
        for (int k = 0; k < H_N; ++k) {
            float a = b3[k];
#pragma unroll
            for (int j = 0; j < H_N; ++j) a = fmaf(h2[j], w3[j * H_N + k], a);
            a4 = fmaf(fast_tanh(a), w4[k], a4);
        }

        const float meval = fast_sigmoid(a4);
        sMeF[mi] = meval;
        sMeH[mi] = (_Float16)meval;
    }

    // ---- scalars / state ----
    const float dt    = t[0] - t[1];
    const float beta  = beta_p[0];
    const float gma   = gamma_p[0];
    const float invdt = 1.0f / dt;

    const float S0 = y[b * 3 + 0];
    const float I0 = y[b * 3 + 1];
    const float R0 = y[b * 3 + 2];
    const float TOT = S0 + I0 + R0;     // SIR total conserved

    // publish I[0] into all 8 rows
    if (tid < 8) sIhR[tid * SIH + 8 - tid] = (_Float16)I0;

    float* __restrict__ diff = out + (size_t)T_N * B_N * 3;
    if (tid < 3) diff[((size_t)(T_N - 1) * B_N + b) * 3 + tid] = 0.0f;

    __syncthreads();   // sMeF/sMeH/pads/I0 visible

    // fixup me weights (chunk-invariant): mf[d-1] = me[960 - L - d]
    float mf[7];
#pragma unroll
    for (int d = 1; d <= 7; ++d) mf[d - 1] = sMeF[T_N - 64 - L - d];

    const float dtb  = dt * beta;
    const float ndtg = -dt * gma;
    const float dt2  = dt * dt;
    const float meT1 = sMeF[T_N - 1];

    float S = S0, I = I0, oS = S0, oI = I0;
    float acc_cur = 0.0f, acc_nxt = 0.0f, pre = 0.0f;
    float carryS = S0, carryI = I0;

    // register me-tables: 128 NAMED scalars (no array, no alloca, no SROA)
#define TBLDECL(k) float rm_##k, rn_##k;
    REP64(TBLDECL)
#undef TBLDECL
    if (wid == 0) {
#define TBLINIT(k)                                                      \
        rm_##k = ((k) < L) ? sMeF[T_N - L + (k)] : 0.0f;                \
        rn_##k = sMeF[T_N - 64 - L + (k)];
        REP64(TBLINIT)
#undef TBLINIT
        // R2: pin every table value into a VGPR. Opaque def -> the compiler
        // cannot rematerialize these as per-step LDS reads inside the chain.
#define TBLPIN(k) asm volatile("" : "+v"(rm_##k), "+v"(rn_##k));
        REP64(TBLPIN)
#undef TBLPIN
    }

    // serial step M_: entering (S,I) = y_{64c+M_-1}; produces y_{64c+M_}.
    // pre was read BEFORE step (M_-1)'s fold -> patch with meT1*I.
    // Longest dependency cycle: I->bI->q->{I',s1->S'} = 3 VALU ops.
#define STEPB(M_, FIRST_)                                               \
    {                                                                   \
        const float sum = (FIRST_) ? pre : fmaf(meT1, I, pre);          \
        float pnx = pre;                                                \
        if ((M_) < 63) pnx = rdlane_i(acc_cur, (M_) + 1);               \
        const float bI = dtb * I;                                       \
        const float i1 = fmaf(ndtg, I, I);                              \
        const float q  = bI * S;                                        \
        const float s1 = S - q;                                         \
        S = fmaf(dt2, sum, s1);                                         \
        I = i1 + q;                                                     \
        const bool cap = (L == (M_));                                   \
        oS = cap ? S : oS;                                              \
        oI = cap ? I : oI;                                              \
        acc_cur = fmaf(rm_##M_, I, acc_cur);                            \
        acc_nxt = fmaf(rn_##M_, I, acc_nxt);                            \
        pre = pnx;                                                      \
    }
#define STEP_GE1(M_) if ((M_) >= 1) STEPB(M_, false)
#define STEP_GE2(M_) if ((M_) >= 2) STEPB(M_, false)

    for (int c = 0; c < 16; ++c) {
        if (wid == 0) {
            if (c == 0) {
                // fold initial I0 (t=0 term); lane0's rm_0 is the 0 pad
                acc_cur = rm_0 * I;
                acc_nxt = rn_0 * I;
                pre = rdlane_i(acc_cur, 1);
                STEPB(1, true)
                REP64(STEP_GE2)
            } else {
                float ac = acc_nxt;
#pragma unroll
                for (int w = 0; w < NDW; ++w) ac += P[c & 1][w][L];
                acc_cur = ac;
                acc_nxt = 0.0f;
                pre = rdlane_i(acc_cur, 0);
                STEPB(0, true)
                REP64(STEP_GE1)
            }

            // ---- chunk epilogue (wave 0) ----
            const int j = 64 * c + L;
            const _Float16 hI = (_Float16)oI;
#pragma unroll
            for (int r = 0; r < 8; ++r) sIhR[r * SIH + 8 + (j - r)] = hI;

            const float oR = TOT - oS - oI;
            const size_t so = ((size_t)j * B_N + b) * 3;
            out[so + 0] = oS;
            out[so + 1] = oI;
            out[so + 2] = oR;

            float sm1 = __shfl_up(oS, 1);
            float im1 = __shfl_up(oI, 1);
            if (L == 0) { sm1 = carryS; im1 = carryI; }
            if (j > 0) {
                const float d0 = (oS - sm1) * invdt;
                const float d1 = (oI - im1) * invdt;
                const float d2 = -d0 - d1;
                const size_t dofs = ((size_t)(j - 1) * B_N + b) * 3;
                diff[dofs + 0] = d0;
                diff[dofs + 1] = d1;
                diff[dofs + 2] = d2;
            }
            carryS = rdlane_i(oS, 63);
            carryI = rdlane_i(oI, 63);
        } else if (c < 15) {
            // history dot for chunk c+1 over tau < 64c (R5 layout, unchanged)
            const int w    = wid - 1;
            const int G    = 8 * c;
            const int idx0 = (T_N - 64 * (c + 1)) - R8;
            float p0 = 0.0f, p1 = 0.0f;
            int s = w;
            for (; s + NDW < G; s += 2 * NDW) {
                const h8_t mv0 = *(const h8_t*)&sMeH[idx0 + 8 * s];
                const h8_t iv0 = *(const h8_t*)&sIhR[iofs + 8 * s];
                const h8_t mv1 = *(const h8_t*)&sMeH[idx0 + 8 * (s + NDW)];
                const h8_t iv1 = *(const h8_t*)&sIhR[iofs + 8 * (s + NDW)];
                DOT8(p0, mv0, iv0)
                DOT8(p1, mv1, iv1)
            }
            if (s < G) {
                const h8_t mv0 = *(const h8_t*)&sMeH[idx0 + 8 * s];
                const h8_t iv0 = *(const h8_t*)&sIhR[iofs + 8 * s];
                DOT8(p0, mv0, iv0)
            }
            float p = p0 + p1;
            if (w == 0) {
                // tail fixup: tau = 64c - d, d = 1..f
#pragma unroll
                for (int d = 1; d <= 7; ++d) {
                    const float ih = (float)sIhR[8 + 64 * c - d];   // row 0
                    if (d <= f) p = fmaf(mf[d - 1], ih, p);
                }
            }
            P[(c + 1) & 1][w][L] = p;
        }
        __syncthreads();
    }
#undef STEPB
#undef STEP_GE1
#undef STEP_GE2
}

// ---------------------------------------------------------------------------
// Launcher
// ---------------------------------------------------------------------------
extern "C" void kernel_launch(void* const* d_in, const int* in_sizes, int n_in,
                              void* d_out, int out_size, void* d_ws, size_t ws_size,
                              hipStream_t stream) {
    const float* t     = (const float*)d_in[0];
    const float* y     = (const float*)d_in[1];
    const float* w1    = (const float*)d_in[2];
    const float* b1    = (const float*)d_in[3];
    const float* w2    = (const float*)d_in[4];
    const float* b2    = (const float*)d_in[5];
    const float* w3    = (const float*)d_in[6];
    const float* b3    = (const float*)d_in[7];
    const float* w4    = (const float*)d_in[8];
    const float* b4    = (const float*)d_in[9];
    const float* beta  = (const float*)d_in[10];
    const float* gamma = (const float*)d_in[11];

    scan_kernel<<<B_N, 512, 0, stream>>>(t, y, w1, b1, w2, b2, w3, b3, w4, b4,
                                         beta, gamma, (float*)d_out);
}